// Round 15
// baseline (148.059 us; speedup 1.0000x reference)
//
#include <hip/hip_runtime.h>

typedef float f32x4 __attribute__((ext_vector_type(4)));
typedef float f32x16 __attribute__((ext_vector_type(16)));
typedef short bf16x8 __attribute__((ext_vector_type(8)));
typedef unsigned short u16;
typedef unsigned int u32;
typedef unsigned int u32x2 __attribute__((ext_vector_type(2)));

#define MFMA(a, b, c) __builtin_amdgcn_mfma_f32_16x16x32_bf16((a), (b), (c), 0, 0, 0)
#define MFMA32(a, b, c) __builtin_amdgcn_mfma_f32_32x32x16_bf16((a), (b), (c), 0, 0, 0)

static __device__ __forceinline__ u16 f2bf(float f) {
    union { float f; u32 u; } v; v.f = f;
    u32 r = v.u + 0x7FFFu + ((v.u >> 16) & 1u);
    return (u16)(r >> 16);
}

// pack two fp32 -> two bf16 in one u32 (a low, b high)
static __device__ __forceinline__ u32 pkbf(float a, float b) {
    u32 ua = __float_as_uint(a) + 0x8000u;
    u32 ub = __float_as_uint(b) + 0x8000u;
    return __builtin_amdgcn_perm(ub, ua, 0x07060302);
}

// async global->LDS DMA, 16B per lane: LDS dest = wave-uniform base + lane*16.
static __device__ __forceinline__ void gll16(const u16* g, u16* l) {
    __builtin_amdgcn_global_load_lds(
        (const __attribute__((address_space(1))) u32*)(const void*)g,
        (__attribute__((address_space(3))) u32*)(void*)l, 16, 0, 0);
}

// barrier with vmcnt drain (DMA fills tracked by vmcnt).
#define BAR_VM() do { \
    asm volatile("s_waitcnt vmcnt(0)" ::: "memory"); \
    __builtin_amdgcn_s_barrier(); \
    asm volatile("" ::: "memory"); \
} while (0)

// barrier draining only LDS ops; in-flight global loads may cross.
#define BAR_LGKM() do { \
    asm volatile("s_waitcnt lgkmcnt(0)" ::: "memory"); \
    __builtin_amdgcn_s_barrier(); \
} while (0)

// ---------------------------------------------------------------------------
// Kernel 1: prep = wcvt (blocks 0..255) + gn_stats (blocks 256..511).
// ---------------------------------------------------------------------------
__global__ __launch_bounds__(256) void prep_kernel(
    const float* __restrict__ wq, const float* __restrict__ wk,
    const float* __restrict__ wv, const float* __restrict__ wo,
    const float* __restrict__ x, u16* __restrict__ Wbf,
    float2* __restrict__ part) {
    int blk = blockIdx.x;
    int t = threadIdx.x;
    if (blk < 256) {
        int base = (blk * 256 + t) * 4;
        int p = base >> 16;
        int off = base & 65535;
        const float* W = (p == 0) ? wq : ((p == 1) ? wk : ((p == 2) ? wv : wo));
        float sc = (p == 0) ? 0.09014009048f : 1.0f;   // log2(e)/16
        float4 v = *(const float4*)(W + off);
        uint2 pk;
        pk.x = pkbf(v.x * sc, v.y * sc);
        pk.y = pkbf(v.z * sc, v.w * sc);
        *(uint2*)(Wbf + base) = pk;
        return;
    }
    int sblk = blk - 256;
    int bg = sblk >> 2, quarter = sblk & 3;
    const float* xp = x + (size_t)bg * 32768 + quarter * 8192;

    float s = 0.f, ss = 0.f;
#pragma unroll
    for (int rep = 0; rep < 8; ++rep) {
        float4 v = *(const float4*)(xp + t * 4 + rep * 1024);
        s += v.x + v.y + v.z + v.w;
        ss += v.x * v.x + v.y * v.y + v.z * v.z + v.w * v.w;
    }
    for (int off = 1; off < 64; off <<= 1) {
        s += __shfl_xor(s, off);
        ss += __shfl_xor(ss, off);
    }
    __shared__ float red[8];
    int lane = t & 63, w = t >> 6;
    if (lane == 0) { red[w] = s; red[4 + w] = ss; }
    __syncthreads();
    if (t == 0) {
        part[sblk] = make_float2(red[0] + red[1] + red[2] + red[3],
                                 red[4] + red[5] + red[6] + red[7]);
    }
}

// ---------------------------------------------------------------------------
// Kernel 2: QKV GEMM, R27: p-FUSED — one block computes Q, K and V for its
// (m0,n0) tile. The GroupNorm'd B panel is built ONCE (was 3x: x read and
// normalized per projection = 25MB fp32 reads + 3x staging VALU; now 8.4MB).
// Three A tiles staged per k-step -> 3x MFMA per staged B byte. m-tile 64:
// acc 3x[2][2] = 48 AGPR, ~125 total regs (natural alloc, no forced bounds),
// LDS 43KB -> 3 blocks/CU. Grid (256,2); x-sharing m-blocks XCD-paired via
// bit-3 encoding. Double-buffer + register prefetch retained.
// ---------------------------------------------------------------------------
__global__ __launch_bounds__(256) void qkv_gemm(
    const float* __restrict__ x, const float* __restrict__ gw,
    const float* __restrict__ gb, const float2* __restrict__ part,
    const u16* __restrict__ Wbf,
    u16* __restrict__ Q, u16* __restrict__ K, u16* __restrict__ V) {
    int b = blockIdx.y;
    int bx = blockIdx.x;
    int m0 = ((bx >> 3) & 3) * 64;
    int n0 = ((bx & 7) | ((bx >> 5) << 3)) * 64;

    __shared__ u16 a_s[2][3][64 * 40];
    __shared__ u16 b_s[2][64 * 40];
    __shared__ float wgt_s[256], bia_s[256];

    int t = threadIdx.x;
    int lane = t & 63, wave = t >> 6;
    int wm = wave & 1, wn = wave >> 1;
    int r = lane & 15, qd = lane >> 4;

    {
        int c = t;
        int g = c >> 3;
        float s = 0.f, ss = 0.f;
#pragma unroll
        for (int q = 0; q < 4; ++q) {
            float2 pp = part[(b * 32 + g) * 4 + q];
            s += pp.x; ss += pp.y;
        }
        float mu = s * (1.f / 32768.f);
        float var = ss * (1.f / 32768.f) - mu * mu;
        float rstd = rsqrtf(var + 1e-5f);
        float wg = gw[c] * rstd;
        wgt_s[c] = wg;
        bia_s[c] = gb[c] - mu * wg;
    }
    __syncthreads();

    f32x4 acc[3][2][2];
#pragma unroll
    for (int p = 0; p < 3; ++p)
#pragma unroll
        for (int i = 0; i < 2; ++i)
#pragma unroll
            for (int j = 0; j < 2; ++j) acc[p][i][j] = (f32x4){0.f, 0.f, 0.f, 0.f};

    int ar = t >> 2;                      // A: 64 rows, 4 threads/row
    int ac = (t & 3) * 8;                 // 8 u16 per thread per proj
    int bn = t & 63;                      // B: n within tile (coalesced)
    int bw = t >> 6;                      // wave = c-granule
    int bswz = ((bn >> 3) & 3) ^ (((bn >> 5) & 1) << 1);
    int bgp = ((bw ^ bswz) << 3);

    uint4 pa[3];
    float pxv[8];
    auto load_regs = [&](int kk) {
#pragma unroll
        for (int p = 0; p < 3; ++p)
            pa[p] = *(const uint4*)(Wbf + p * 65536 + (m0 + ar) * 256 + kk + ac);
        const float* xcol = x + (size_t)(b * 256 + kk + bw * 8) * 4096 + n0 + bn;
#pragma unroll
        for (int j = 0; j < 8; ++j) pxv[j] = xcol[(size_t)j * 4096];
    };
    auto write_buf = [&](int bsel, int kk) {
#pragma unroll
        for (int p = 0; p < 3; ++p)
            *(uint4*)(a_s[bsel][p] + ar * 40 + ac) = pa[p];
        u32* dst = (u32*)(b_s[bsel] + bn * 40 + bgp);
#pragma unroll
        for (int j = 0; j < 4; ++j) {
            int c = kk + bw * 8 + 2 * j;
            dst[j] = pkbf(pxv[2 * j] * wgt_s[c] + bia_s[c],
                          pxv[2 * j + 1] * wgt_s[c + 1] + bia_s[c + 1]);
        }
    };

    load_regs(0);
    write_buf(0, 0);
    BAR_LGKM();

    for (int it = 0; it < 8; ++it) {
        int cur = it & 1;
        bool more = (it + 1) < 8;
        if (more) load_regs((it + 1) * 32);

        bf16x8 af[3][2], bf[2];
#pragma unroll
        for (int p = 0; p < 3; ++p)
#pragma unroll
            for (int mt = 0; mt < 2; ++mt)
                af[p][mt] = *(const bf16x8*)(a_s[cur][p] +
                    (wm * 32 + mt * 16 + r) * 40 + qd * 8);
#pragma unroll
        for (int nt = 0; nt < 2; ++nt) {
            int row = wn * 32 + nt * 16 + r;
            int rswz = ((row >> 3) & 3) ^ (((row >> 5) & 1) << 1);
            bf[nt] = *(const bf16x8*)(b_s[cur] + row * 40 + ((qd ^ rswz) << 3));
        }
#pragma unroll
        for (int mt = 0; mt < 2; ++mt)
#pragma unroll
            for (int nt = 0; nt < 2; ++nt) {
                acc[0][mt][nt] = MFMA(af[0][mt], bf[nt], acc[0][mt][nt]);
                acc[1][mt][nt] = MFMA(af[1][mt], bf[nt], acc[1][mt][nt]);
                acc[2][mt][nt] = MFMA(bf[nt], af[2][mt], acc[2][mt][nt]);
            }

        if (more) write_buf(cur ^ 1, (it + 1) * 32);
        BAR_LGKM();
    }

    // epilogue: Q and K ([b][h][s][d], per-lane 4-row scatter)
#pragma unroll
    for (int p = 0; p < 2; ++p) {
        u16* dst = (p == 0) ? Q : K;
#pragma unroll
        for (int mt = 0; mt < 2; ++mt) {
#pragma unroll
            for (int nt = 0; nt < 2; ++nt) {
                int o0 = m0 + wm * 32 + mt * 16 + qd * 4;
                int s = n0 + wn * 32 + nt * 16 + r;
                int h = o0 >> 6, d0 = o0 & 63;
                uint2 pk;
                pk.x = pkbf(acc[p][mt][nt][0], acc[p][mt][nt][1]);
                pk.y = pkbf(acc[p][mt][nt][2], acc[p][mt][nt][3]);
                *(uint2*)(dst + ((size_t)((b * 4 + h) * 4096 + s)) * 64 + d0) = pk;
            }
        }
    }
    // V ([b][h][d][s] transposed layout)
#pragma unroll
    for (int mt = 0; mt < 2; ++mt) {
#pragma unroll
        for (int nt = 0; nt < 2; ++nt) {
            int o = m0 + wm * 32 + mt * 16 + r;
            int h = o >> 6, d = o & 63;
            int sb = n0 + wn * 32 + nt * 16 + qd * 4;
            uint2 pk;
            pk.x = pkbf(acc[2][mt][nt][0], acc[2][mt][nt][1]);
            pk.y = pkbf(acc[2][mt][nt][2], acc[2][mt][nt][3]);
            *(uint2*)(V + ((size_t)((b * 4 + h) * 64 + d)) * 4096 + sb) = pk;
        }
    }
}

// ---------------------------------------------------------------------------
// Kernel 3: flash attention (R26 structure, frozen: QT=1 + DMA staging +
// 2-deep qk/sm_pv pipeline, 64 VGPR + 32 AGPR, 4 blocks/CU, nsplit=4).
// ---------------------------------------------------------------------------
template <int QT>
__global__ __launch_bounds__(256, QT == 1 ? 4 : 2) void attn_kernel(
    const u16* __restrict__ Q, const u16* __restrict__ K,
    const u16* __restrict__ V, u16* __restrict__ Opart,
    float* __restrict__ Lpart, int nk32) {
    int bh = blockIdx.x & 7, sp = blockIdx.x >> 3;
    int qb = blockIdx.y;
    int t = threadIdx.x, lane = t & 63, w = t >> 6;
    int qn = lane & 31, h = lane >> 5;

    const size_t bhoff = (size_t)bh * 4096 * 64;
    int q0 = (qb * 4 + w) * (32 * QT);
    int kbase = sp * nk32 * 32;

    __shared__ u16 smem[16384];

    bf16x8 qf[4];
#pragma unroll
    for (int c = 0; c < 4; ++c)
        qf[c] = *(const bf16x8*)(Q + bhoff +
            (size_t)(q0 + qn) * 64 + c * 16 + h * 8);

    f32x16 oacc[2];
#pragma unroll
    for (int dt = 0; dt < 2; ++dt)
#pragma unroll
        for (int i = 0; i < 16; ++i) oacc[dt][i] = 0.f;
    float lacc = 0.f;

    const u16* Kp = K + bhoff;
    const u16* Vp = V + bhoff;

    int gs = (lane & 7) ^ (lane >> 3);
    int rbase = (w & 1) * 32 + (lane >> 3);

    auto fill = [&](int bufsel, int kp) {
        u16* ld = smem + bufsel * 8192 + w * 2048;
        if (w < 2) {
            const u16* s = Kp + (size_t)(kp + rbase) * 64 + gs * 8;
#pragma unroll
            for (int j = 0; j < 4; ++j) gll16(s + j * 512, ld + j * 512);
        } else {
            const u16* s = Vp + (size_t)rbase * 4096 + kp + gs * 8;
#pragma unroll
            for (int j = 0; j < 4; ++j) gll16(s + j * 32768, ld + j * 512);
        }
    };

    int sw = qn & 7;
    auto qk = [&](const u16* buf, int j, f32x16& s) {
        bf16x8 kf[4];
        int kr = j * 32 + qn;
#pragma unroll
        for (int c = 0; c < 4; ++c)
            kf[c] = *(const bf16x8*)(buf + kr * 64 + (((c * 2 + h) ^ sw) << 3));
#pragma unroll
        for (int i = 0; i < 16; ++i) s[i] = 0.f;
        __builtin_amdgcn_s_setprio(1);
#pragma unroll
        for (int c = 0; c < 4; ++c) s = MFMA32(kf[c], qf[c], s);
        __builtin_amdgcn_s_setprio(0);
    };
    auto sm_pv = [&](const u16* buf, int j, const f32x16& s) {
        bf16x8 vf[2][2];
#pragma unroll
        for (int dt = 0; dt < 2; ++dt) {
            int d = dt * 32 + qn;
#pragma unroll
            for (int kc = 0; kc < 2; ++kc) {
                int g = j * 4 + kc * 2 + h;
                vf[dt][kc] = *(const bf16x8*)(buf + 4096 + d * 64 + ((g ^ sw) << 3));
            }
        }
        float e[16];
#pragma unroll
        for (int i = 0; i < 16; ++i)
            e[i] = __builtin_amdgcn_exp2f(s[i]);
        float t0 = (e[0] + e[1]) + (e[2] + e[3]);
        float t1 = (e[4] + e[5]) + (e[6] + e[7]);
        float t2 = (e[8] + e[9]) + (e[10] + e[11]);
        float t3 = (e[12] + e[13]) + (e[14] + e[15]);
        lacc += (t0 + t1) + (t2 + t3);

        u32 p[8];
#pragma unroll
        for (int i = 0; i < 8; ++i) p[i] = pkbf(e[2 * i], e[2 * i + 1]);

        u32x2 r0 = __builtin_amdgcn_permlane32_swap(p[0], p[2], false, false);
        u32x2 r1 = __builtin_amdgcn_permlane32_swap(p[1], p[3], false, false);
        u32x2 r2 = __builtin_amdgcn_permlane32_swap(p[4], p[6], false, false);
        u32x2 r3 = __builtin_amdgcn_permlane32_swap(p[5], p[7], false, false);
        uint4 pau = {r0[0], r1[0], r0[1], r1[1]};
        uint4 pbu = {r2[0], r3[0], r2[1], r3[1]};
        bf16x8 pA = *(const bf16x8*)&pau;
        bf16x8 pB = *(const bf16x8*)&pbu;

        __builtin_amdgcn_s_setprio(1);
#pragma unroll
        for (int dt = 0; dt < 2; ++dt) {
            oacc[dt] = MFMA32(vf[dt][0], pA, oacc[dt]);
            oacc[dt] = MFMA32(vf[dt][1], pB, oacc[dt]);
        }
        __builtin_amdgcn_s_setprio(0);
    };

    int npair = nk32 >> 1;
    fill(0, kbase);
    if (npair > 1) fill(1, kbase + 64);
    BAR_VM();

    for (int i = 0; i < npair; ++i) {
        const u16* cur = smem + (i & 1) * 8192;
        f32x16 sA, sB;
        qk(cur, 0, sA);
        qk(cur, 1, sB);
        sm_pv(cur, 0, sA);
        sm_pv(cur, 1, sB);
        BAR_VM();
        if (i + 2 < npair) fill(i & 1, kbase + (i + 2) * 64);
    }

    float lfull = lacc + __shfl_xor(lacc, 32);

    u16* my = smem + w * (32 * 72);
    size_t obase = ((size_t)sp * 8 + bh) * 4096 + q0;
#pragma unroll
    for (int dt = 0; dt < 2; ++dt) {
#pragma unroll
        for (int g = 0; g < 4; ++g) {
            int d0 = g * 8 + h * 4 + dt * 32;
            uint2 pk;
            pk.x = pkbf(oacc[dt][4 * g], oacc[dt][4 * g + 1]);
            pk.y = pkbf(oacc[dt][4 * g + 2], oacc[dt][4 * g + 3]);
            *(uint2*)(my + qn * 72 + d0) = pk;
        }
    }
#pragma unroll
    for (int rr = 0; rr < 4; ++rr) {
        int row = rr * 8 + (lane >> 3), ch = lane & 7;
        uint4 v = *(const uint4*)(my + row * 72 + ch * 8);
        *(uint4*)(Opart + (obase + row) * 64 + ch * 8) = v;
    }
    if (h == 0) Lpart[obase + qn] = lfull;
}

// ---------------------------------------------------------------------------
// Kernel 4: combine nsplit partials, normalize, write attnT[b][s][c] bf16.
// ---------------------------------------------------------------------------
__global__ __launch_bounds__(256) void attn_combine(
    const u16* __restrict__ Opart, const float* __restrict__ Lpart,
    u16* __restrict__ attnT, int nsplit) {
    int t = threadIdx.x;
    int gr = blockIdx.x * 64 + (t >> 2);      // bh*4096+q
    int d0 = (t & 3) * 16;

    float l = 0.f;
    for (int s = 0; s < nsplit; ++s) l += Lpart[(size_t)s * 32768 + gr];
    float inv = 1.f / l;

    float acc[16];
#pragma unroll
    for (int i = 0; i < 16; ++i) acc[i] = 0.f;
    for (int s = 0; s < nsplit; ++s) {
        const u16* p = Opart + ((size_t)s * 32768 + gr) * 64 + d0;
        uint4 a = *(const uint4*)(p);
        uint4 bq = *(const uint4*)(p + 8);
        const u32* ap = (const u32*)&a;
        const u32* bp = (const u32*)&bq;
#pragma unroll
        for (int j = 0; j < 4; ++j) {
            acc[2 * j]     += __uint_as_float(ap[j] << 16);
            acc[2 * j + 1] += __uint_as_float(ap[j] & 0xFFFF0000u);
            acc[8 + 2 * j]     += __uint_as_float(bp[j] << 16);
            acc[8 + 2 * j + 1] += __uint_as_float(bp[j] & 0xFFFF0000u);
        }
    }
    u32 pk[8];
#pragma unroll
    for (int j = 0; j < 8; ++j)
        pk[j] = pkbf(acc[2 * j] * inv, acc[2 * j + 1] * inv);

    int bh = gr >> 12, q = gr & 4095;
    int b = bh >> 2, hh = bh & 3;
    u16* dst = attnT + ((size_t)(b * 4096 + q)) * 256 + hh * 64 + d0;
    *(uint4*)(dst) = make_uint4(pk[0], pk[1], pk[2], pk[3]);
    *(uint4*)(dst + 8) = make_uint4(pk[4], pk[5], pk[6], pk[7]);
}

// ---------------------------------------------------------------------------
// Kernel 5: output GEMM + bias + residual (R24 state, frozen).
// ---------------------------------------------------------------------------
__global__ __launch_bounds__(256) void out_gemm(
    const u16* __restrict__ attnT, const u16* __restrict__ W3,
    const float* __restrict__ bo, const float* __restrict__ x,
    float* __restrict__ out) {
    int b = blockIdx.y;
    int bx = blockIdx.x;
    int m0 = ((bx >> 3) & 3) * 64;
    int n0 = ((bx & 7) | ((bx >> 5) << 3)) * 64;

    __shared__ u16 a_s[2][64 * 40];
    __shared__ u16 b_s[2][64 * 40];

    int t = threadIdx.x;
    int lane = t & 63, wave = t >> 6;
    int wm = wave & 1, wn = wave >> 1;
    int r = lane & 15, qd = lane >> 4;

    const u16* Bsrc = attnT + (size_t)b * 4096 * 256;

    f32x4 acc[2][2];
#pragma unroll
    for (int i = 0; i < 2; ++i)
#pragma unroll
        for (int j = 0; j < 2; ++j) acc[i][j] = (f32x4){0.f, 0.f, 0.f, 0.f};

    int u = t & 127;
    int srow = u >> 1;
    int scp = (u & 1) * 16;

    uint4 p0, p1;
    auto load_regs = [&](int kk) {
        const u16* src = (t < 128)
            ? W3 + (m0 + srow) * 256 + kk + scp
            : Bsrc + (size_t)(n0 + srow) * 256 + kk + scp;
        p0 = *(const uint4*)(src);
        p1 = *(const uint4*)(src + 8);
    };
    auto write_buf = [&](int bsel) {
        u16* dst = (t < 128) ? (a_s[bsel] + srow * 40 + scp)
                             : (b_s[bsel] + srow * 40 + scp);
        *(uint4*)(dst) = p0;
        *(uint4*)(dst + 8) = p1;
    };

    load_regs(0);
    write_buf(0);
    BAR_LGKM();

    for (int it = 0; it < 8; ++it) {
        int cur = it & 1;
        bool more = (it + 1) < 8;
        if (more) load_regs((it + 1) * 32);

        bf16x8 af[2], bf[2];
#pragma unroll
        for (int mt = 0; mt < 2; ++mt)
            af[mt] = *(const bf16x8*)(a_s[cur] + (wm * 32 + mt * 16 + r) * 40 + qd * 8);
#pragma unroll
        for (int nt = 0; nt < 2; ++nt)
            bf[nt] = *(const bf16x8*)(b_s[cur] + (wn * 32 + nt * 16 + r) * 40 + qd * 8);
#pragma unroll
        for (int mt = 0; mt < 2; ++mt)
#pragma unroll
            for (int nt = 0; nt < 2; ++nt)
                acc[mt][nt] = MFMA(af[mt], bf[nt], acc[mt][nt]);

        if (more) write_buf(cur ^ 1);
        BAR_LGKM();
    }

#pragma unroll
    for (int mt = 0; mt < 2; ++mt) {
#pragma unroll
        for (int nt = 0; nt < 2; ++nt) {
#pragma unroll
            for (int j = 0; j < 4; ++j) {
                int o = m0 + wm * 32 + mt * 16 + qd * 4 + j;
                int s = n0 + wn * 32 + nt * 16 + r;
                size_t idx = (size_t)(b * 256 + o) * 4096 + s;
                out[idx] = acc[mt][nt][j] + bo[o] + x[idx];
            }
        }
    }
}

// ---------------------------------------------------------------------------
extern "C" void kernel_launch(void* const* d_in, const int* in_sizes, int n_in,
                              void* d_out, int out_size, void* d_ws, size_t ws_size,
                              hipStream_t stream) {
    const float* x = (const float*)d_in[0];
    const float* gn_w = (const float*)d_in[1];
    const float* gn_b = (const float*)d_in[2];
    const float* wq = (const float*)d_in[3];
    const float* wk = (const float*)d_in[4];
    const float* wv = (const float*)d_in[5];
    const float* wo = (const float*)d_in[6];
    const float* bo = (const float*)d_in[7];
    float* out = (float*)d_out;

    char* ws = (char*)d_ws;
    u16* attnT = (u16*)(ws);                        // [0,4M)
    u16* Q     = (u16*)(ws + (4u << 20));           // [b][h][s][d] (scaled log2e/16)
    u16* Kp    = (u16*)(ws + (8u << 20));           // [b][h][s][d]
    u16* Vp    = (u16*)(ws + (12u << 20));          // [b][h][d][s]
    u16* Wbf   = (u16*)(ws + (16u << 20));          // 512 KB
    float2* part = (float2*)(ws + (16u << 20) + 524288);

    size_t opart_off = (size_t)17 << 20;
    size_t osplit = 8ull * 4096 * 64 * 2;            // 4 MB per split
    int nsplit = (ws_size >= opart_off + 4 * osplit + 4ull * 32768 * 4 + 4096) ? 4 : 2;
    u16* Opart = (u16*)(ws + opart_off);
    float* Lpart = (float*)(ws + opart_off + (size_t)nsplit * osplit);

    prep_kernel<<<512, 256, 0, stream>>>(wq, wk, wv, wo, x, Wbf, part);
    qkv_gemm<<<dim3(256, 2), 256, 0, stream>>>(x, gn_w, gn_b, part, Wbf, Q, Kp, Vp);
    attn_kernel<1><<<dim3(8 * nsplit, 32), 256, 0, stream>>>(
        Q, Kp, Vp, Opart, Lpart, 128 / nsplit);
    attn_combine<<<512, 256, 0, stream>>>(Opart, Lpart, attnT, nsplit);
    out_gemm<<<dim3(256, 2), 256, 0, stream>>>(attnT, Wbf + 3 * 65536, bo, x, out);
}

// Round 16
// 139.693 us; speedup vs baseline: 1.0599x; 1.0599x over previous
//
#include <hip/hip_runtime.h>

typedef float f32x4 __attribute__((ext_vector_type(4)));
typedef float f32x16 __attribute__((ext_vector_type(16)));
typedef short bf16x8 __attribute__((ext_vector_type(8)));
typedef unsigned short u16;
typedef unsigned int u32;
typedef unsigned int u32x2 __attribute__((ext_vector_type(2)));

#define MFMA(a, b, c) __builtin_amdgcn_mfma_f32_16x16x32_bf16((a), (b), (c), 0, 0, 0)
#define MFMA32(a, b, c) __builtin_amdgcn_mfma_f32_32x32x16_bf16((a), (b), (c), 0, 0, 0)

static __device__ __forceinline__ u16 f2bf(float f) {
    union { float f; u32 u; } v; v.f = f;
    u32 r = v.u + 0x7FFFu + ((v.u >> 16) & 1u);
    return (u16)(r >> 16);
}

// pack two fp32 -> two bf16 in one u32 (a low, b high)
static __device__ __forceinline__ u32 pkbf(float a, float b) {
    u32 ua = __float_as_uint(a) + 0x8000u;
    u32 ub = __float_as_uint(b) + 0x8000u;
    return __builtin_amdgcn_perm(ub, ua, 0x07060302);
}

// async global->LDS DMA, 16B per lane: LDS dest = wave-uniform base + lane*16.
static __device__ __forceinline__ void gll16(const u16* g, u16* l) {
    __builtin_amdgcn_global_load_lds(
        (const __attribute__((address_space(1))) u32*)(const void*)g,
        (__attribute__((address_space(3))) u32*)(void*)l, 16, 0, 0);
}

// barrier with vmcnt drain (DMA fills tracked by vmcnt).
#define BAR_VM() do { \
    asm volatile("s_waitcnt vmcnt(0)" ::: "memory"); \
    __builtin_amdgcn_s_barrier(); \
    asm volatile("" ::: "memory"); \
} while (0)

// barrier draining only LDS ops; in-flight global loads may cross.
#define BAR_LGKM() do { \
    asm volatile("s_waitcnt lgkmcnt(0)" ::: "memory"); \
    __builtin_amdgcn_s_barrier(); \
} while (0)

// ---------------------------------------------------------------------------
// Kernel 1: prep = wcvt (blocks 0..255) + gn_stats (blocks 256..511).
// ---------------------------------------------------------------------------
__global__ __launch_bounds__(256) void prep_kernel(
    const float* __restrict__ wq, const float* __restrict__ wk,
    const float* __restrict__ wv, const float* __restrict__ wo,
    const float* __restrict__ x, u16* __restrict__ Wbf,
    float2* __restrict__ part) {
    int blk = blockIdx.x;
    int t = threadIdx.x;
    if (blk < 256) {
        int base = (blk * 256 + t) * 4;
        int p = base >> 16;
        int off = base & 65535;
        const float* W = (p == 0) ? wq : ((p == 1) ? wk : ((p == 2) ? wv : wo));
        float sc = (p == 0) ? 0.09014009048f : 1.0f;   // log2(e)/16
        float4 v = *(const float4*)(W + off);
        uint2 pk;
        pk.x = pkbf(v.x * sc, v.y * sc);
        pk.y = pkbf(v.z * sc, v.w * sc);
        *(uint2*)(Wbf + base) = pk;
        return;
    }
    int sblk = blk - 256;
    int bg = sblk >> 2, quarter = sblk & 3;
    const float* xp = x + (size_t)bg * 32768 + quarter * 8192;

    float s = 0.f, ss = 0.f;
#pragma unroll
    for (int rep = 0; rep < 8; ++rep) {
        float4 v = *(const float4*)(xp + t * 4 + rep * 1024);
        s += v.x + v.y + v.z + v.w;
        ss += v.x * v.x + v.y * v.y + v.z * v.z + v.w * v.w;
    }
    for (int off = 1; off < 64; off <<= 1) {
        s += __shfl_xor(s, off);
        ss += __shfl_xor(ss, off);
    }
    __shared__ float red[8];
    int lane = t & 63, w = t >> 6;
    if (lane == 0) { red[w] = s; red[4 + w] = ss; }
    __syncthreads();
    if (t == 0) {
        part[sblk] = make_float2(red[0] + red[1] + red[2] + red[3],
                                 red[4] + red[5] + red[6] + red[7]);
    }
}

// ---------------------------------------------------------------------------
// Kernel 2: QKV GEMM, fused GroupNorm B-stage (R24 state: separate blocks
// per projection, coalesced B-stage, pkbf packing, XCD pairing, dbuf).
// R27's p-fusion (shared B, 3x A) regressed +8us — reverted.
// ---------------------------------------------------------------------------
__global__ __launch_bounds__(256) void qkv_gemm(
    const float* __restrict__ x, const float* __restrict__ gw,
    const float* __restrict__ gb, const float2* __restrict__ part,
    const u16* __restrict__ Wbf,
    u16* __restrict__ Q, u16* __restrict__ K, u16* __restrict__ V) {
    int b = blockIdx.y & 1;
    int p = blockIdx.y >> 1;
    const u16* W = Wbf + p * 65536;
    int bx = blockIdx.x;
    int m0 = ((bx >> 3) & 1) * 128;
    int n0 = ((bx & 7) | ((bx >> 4) << 3)) * 64;

    __shared__ u16 a_s[2][128 * 40];
    __shared__ u16 b_s[2][64 * 40];
    __shared__ float wgt_s[256], bia_s[256];

    int t = threadIdx.x;
    int lane = t & 63, wave = t >> 6;
    int wm = wave & 1, wn = wave >> 1;
    int r = lane & 15, qd = lane >> 4;

    {
        int c = t;
        int g = c >> 3;
        float s = 0.f, ss = 0.f;
#pragma unroll
        for (int q = 0; q < 4; ++q) {
            float2 pp = part[(b * 32 + g) * 4 + q];
            s += pp.x; ss += pp.y;
        }
        float mu = s * (1.f / 32768.f);
        float var = ss * (1.f / 32768.f) - mu * mu;
        float rstd = rsqrtf(var + 1e-5f);
        float wg = gw[c] * rstd;
        wgt_s[c] = wg;
        bia_s[c] = gb[c] - mu * wg;
    }
    __syncthreads();

    f32x4 acc[4][2];
#pragma unroll
    for (int i = 0; i < 4; ++i)
#pragma unroll
        for (int j = 0; j < 2; ++j) acc[i][j] = (f32x4){0.f, 0.f, 0.f, 0.f};

    int srow = t >> 1;
    int scp = (t & 1) * 16;
    int bn = t & 63;                     // n within tile (lane -> coalesced)
    int bw = t >> 6;                     // wave = logical c-granule
    int bswz = ((bn >> 3) & 3) ^ (((bn >> 5) & 1) << 1);
    int bgp = ((bw ^ bswz) << 3);

    uint4 pa0, pa1;
    float pxv[8];
    auto load_regs = [&](int kk) {
        const u16* src = W + (m0 + srow) * 256 + kk + scp;
        pa0 = *(const uint4*)(src);
        pa1 = *(const uint4*)(src + 8);
        const float* xcol = x + (size_t)(b * 256 + kk + bw * 8) * 4096 + n0 + bn;
#pragma unroll
        for (int j = 0; j < 8; ++j) pxv[j] = xcol[(size_t)j * 4096];
    };
    auto write_buf = [&](int bsel, int kk) {
        *(uint4*)(a_s[bsel] + srow * 40 + scp) = pa0;
        *(uint4*)(a_s[bsel] + srow * 40 + scp + 8) = pa1;
        u32* dst = (u32*)(b_s[bsel] + bn * 40 + bgp);
#pragma unroll
        for (int j = 0; j < 4; ++j) {
            int c = kk + bw * 8 + 2 * j;
            dst[j] = pkbf(pxv[2 * j] * wgt_s[c] + bia_s[c],
                          pxv[2 * j + 1] * wgt_s[c + 1] + bia_s[c + 1]);
        }
    };

    load_regs(0);
    write_buf(0, 0);
    BAR_LGKM();

    for (int it = 0; it < 8; ++it) {
        int cur = it & 1;
        bool more = (it + 1) < 8;
        if (more) load_regs((it + 1) * 32);

        bf16x8 af[4], bf[2];
#pragma unroll
        for (int mt = 0; mt < 4; ++mt)
            af[mt] = *(const bf16x8*)(a_s[cur] + (wm * 64 + mt * 16 + r) * 40 + qd * 8);
#pragma unroll
        for (int nt = 0; nt < 2; ++nt) {
            int row = wn * 32 + nt * 16 + r;
            int rswz = ((row >> 3) & 3) ^ (((row >> 5) & 1) << 1);
            bf[nt] = *(const bf16x8*)(b_s[cur] + row * 40 + ((qd ^ rswz) << 3));
        }
        if (p == 2) {
#pragma unroll
            for (int mt = 0; mt < 4; ++mt)
#pragma unroll
                for (int nt = 0; nt < 2; ++nt)
                    acc[mt][nt] = MFMA(bf[nt], af[mt], acc[mt][nt]);
        } else {
#pragma unroll
            for (int mt = 0; mt < 4; ++mt)
#pragma unroll
                for (int nt = 0; nt < 2; ++nt)
                    acc[mt][nt] = MFMA(af[mt], bf[nt], acc[mt][nt]);
        }

        if (more) write_buf(cur ^ 1, (it + 1) * 32);
        BAR_LGKM();
    }

    if (p < 2) {
        u16* dst = (p == 0) ? Q : K;
#pragma unroll
        for (int mt = 0; mt < 4; ++mt) {
#pragma unroll
            for (int nt = 0; nt < 2; ++nt) {
                int o0 = m0 + wm * 64 + mt * 16 + qd * 4;
                int s = n0 + wn * 32 + nt * 16 + r;
                int h = o0 >> 6, d0 = o0 & 63;
                uint2 pk;
                pk.x = pkbf(acc[mt][nt][0], acc[mt][nt][1]);
                pk.y = pkbf(acc[mt][nt][2], acc[mt][nt][3]);
                *(uint2*)(dst + ((size_t)((b * 4 + h) * 4096 + s)) * 64 + d0) = pk;
            }
        }
    } else {
#pragma unroll
        for (int mt = 0; mt < 4; ++mt) {
#pragma unroll
            for (int nt = 0; nt < 2; ++nt) {
                int o = m0 + wm * 64 + mt * 16 + r;
                int h = o >> 6, d = o & 63;
                int sb = n0 + wn * 32 + nt * 16 + qd * 4;
                uint2 pk;
                pk.x = pkbf(acc[mt][nt][0], acc[mt][nt][1]);
                pk.y = pkbf(acc[mt][nt][2], acc[mt][nt][3]);
                *(uint2*)(V + ((size_t)((b * 4 + h) * 64 + d)) * 4096 + sb) = pk;
            }
        }
    }
}

// ---------------------------------------------------------------------------
// Kernel 3: flash attention (R26: QT=1 + DMA staging + 2-deep qk/sm_pv
// pipeline, 64 VGPR + 32 AGPR, 4 blocks/CU, nsplit=4). Best measured.
// ---------------------------------------------------------------------------
template <int QT>
__global__ __launch_bounds__(256, QT == 1 ? 4 : 2) void attn_kernel(
    const u16* __restrict__ Q, const u16* __restrict__ K,
    const u16* __restrict__ V, u16* __restrict__ Opart,
    float* __restrict__ Lpart, int nk32) {
    int bh = blockIdx.x & 7, sp = blockIdx.x >> 3;
    int qb = blockIdx.y;
    int t = threadIdx.x, lane = t & 63, w = t >> 6;
    int qn = lane & 31, h = lane >> 5;

    const size_t bhoff = (size_t)bh * 4096 * 64;
    int q0 = (qb * 4 + w) * (32 * QT);
    int kbase = sp * nk32 * 32;

    __shared__ u16 smem[16384];

    bf16x8 qf[4];
#pragma unroll
    for (int c = 0; c < 4; ++c)
        qf[c] = *(const bf16x8*)(Q + bhoff +
            (size_t)(q0 + qn) * 64 + c * 16 + h * 8);

    f32x16 oacc[2];
#pragma unroll
    for (int dt = 0; dt < 2; ++dt)
#pragma unroll
        for (int i = 0; i < 16; ++i) oacc[dt][i] = 0.f;
    float lacc = 0.f;

    const u16* Kp = K + bhoff;
    const u16* Vp = V + bhoff;

    int gs = (lane & 7) ^ (lane >> 3);
    int rbase = (w & 1) * 32 + (lane >> 3);

    auto fill = [&](int bufsel, int kp) {
        u16* ld = smem + bufsel * 8192 + w * 2048;
        if (w < 2) {
            const u16* s = Kp + (size_t)(kp + rbase) * 64 + gs * 8;
#pragma unroll
            for (int j = 0; j < 4; ++j) gll16(s + j * 512, ld + j * 512);
        } else {
            const u16* s = Vp + (size_t)rbase * 4096 + kp + gs * 8;
#pragma unroll
            for (int j = 0; j < 4; ++j) gll16(s + j * 32768, ld + j * 512);
        }
    };

    int sw = qn & 7;
    auto qk = [&](const u16* buf, int j, f32x16& s) {
        bf16x8 kf[4];
        int kr = j * 32 + qn;
#pragma unroll
        for (int c = 0; c < 4; ++c)
            kf[c] = *(const bf16x8*)(buf + kr * 64 + (((c * 2 + h) ^ sw) << 3));
#pragma unroll
        for (int i = 0; i < 16; ++i) s[i] = 0.f;
        __builtin_amdgcn_s_setprio(1);
#pragma unroll
        for (int c = 0; c < 4; ++c) s = MFMA32(kf[c], qf[c], s);
        __builtin_amdgcn_s_setprio(0);
    };
    auto sm_pv = [&](const u16* buf, int j, const f32x16& s) {
        bf16x8 vf[2][2];
#pragma unroll
        for (int dt = 0; dt < 2; ++dt) {
            int d = dt * 32 + qn;
#pragma unroll
            for (int kc = 0; kc < 2; ++kc) {
                int g = j * 4 + kc * 2 + h;
                vf[dt][kc] = *(const bf16x8*)(buf + 4096 + d * 64 + ((g ^ sw) << 3));
            }
        }
        float e[16];
#pragma unroll
        for (int i = 0; i < 16; ++i)
            e[i] = __builtin_amdgcn_exp2f(s[i]);
        float t0 = (e[0] + e[1]) + (e[2] + e[3]);
        float t1 = (e[4] + e[5]) + (e[6] + e[7]);
        float t2 = (e[8] + e[9]) + (e[10] + e[11]);
        float t3 = (e[12] + e[13]) + (e[14] + e[15]);
        lacc += (t0 + t1) + (t2 + t3);

        u32 p[8];
#pragma unroll
        for (int i = 0; i < 8; ++i) p[i] = pkbf(e[2 * i], e[2 * i + 1]);

        u32x2 r0 = __builtin_amdgcn_permlane32_swap(p[0], p[2], false, false);
        u32x2 r1 = __builtin_amdgcn_permlane32_swap(p[1], p[3], false, false);
        u32x2 r2 = __builtin_amdgcn_permlane32_swap(p[4], p[6], false, false);
        u32x2 r3 = __builtin_amdgcn_permlane32_swap(p[5], p[7], false, false);
        uint4 pau = {r0[0], r1[0], r0[1], r1[1]};
        uint4 pbu = {r2[0], r3[0], r2[1], r3[1]};
        bf16x8 pA = *(const bf16x8*)&pau;
        bf16x8 pB = *(const bf16x8*)&pbu;

        __builtin_amdgcn_s_setprio(1);
#pragma unroll
        for (int dt = 0; dt < 2; ++dt) {
            oacc[dt] = MFMA32(vf[dt][0], pA, oacc[dt]);
            oacc[dt] = MFMA32(vf[dt][1], pB, oacc[dt]);
        }
        __builtin_amdgcn_s_setprio(0);
    };

    int npair = nk32 >> 1;
    fill(0, kbase);
    if (npair > 1) fill(1, kbase + 64);
    BAR_VM();

    for (int i = 0; i < npair; ++i) {
        const u16* cur = smem + (i & 1) * 8192;
        f32x16 sA, sB;
        qk(cur, 0, sA);
        qk(cur, 1, sB);
        sm_pv(cur, 0, sA);
        sm_pv(cur, 1, sB);
        BAR_VM();
        if (i + 2 < npair) fill(i & 1, kbase + (i + 2) * 64);
    }

    float lfull = lacc + __shfl_xor(lacc, 32);

    u16* my = smem + w * (32 * 72);
    size_t obase = ((size_t)sp * 8 + bh) * 4096 + q0;
#pragma unroll
    for (int dt = 0; dt < 2; ++dt) {
#pragma unroll
        for (int g = 0; g < 4; ++g) {
            int d0 = g * 8 + h * 4 + dt * 32;
            uint2 pk;
            pk.x = pkbf(oacc[dt][4 * g], oacc[dt][4 * g + 1]);
            pk.y = pkbf(oacc[dt][4 * g + 2], oacc[dt][4 * g + 3]);
            *(uint2*)(my + qn * 72 + d0) = pk;
        }
    }
#pragma unroll
    for (int rr = 0; rr < 4; ++rr) {
        int row = rr * 8 + (lane >> 3), ch = lane & 7;
        uint4 v = *(const uint4*)(my + row * 72 + ch * 8);
        *(uint4*)(Opart + (obase + row) * 64 + ch * 8) = v;
    }
    if (h == 0) Lpart[obase + qn] = lfull;
}

// ---------------------------------------------------------------------------
// Kernel 4: combine nsplit partials, normalize, write attnT[b][s][c] bf16.
// ---------------------------------------------------------------------------
__global__ __launch_bounds__(256) void attn_combine(
    const u16* __restrict__ Opart, const float* __restrict__ Lpart,
    u16* __restrict__ attnT, int nsplit) {
    int t = threadIdx.x;
    int gr = blockIdx.x * 64 + (t >> 2);      // bh*4096+q
    int d0 = (t & 3) * 16;

    float l = 0.f;
    for (int s = 0; s < nsplit; ++s) l += Lpart[(size_t)s * 32768 + gr];
    float inv = 1.f / l;

    float acc[16];
#pragma unroll
    for (int i = 0; i < 16; ++i) acc[i] = 0.f;
    for (int s = 0; s < nsplit; ++s) {
        const u16* p = Opart + ((size_t)s * 32768 + gr) * 64 + d0;
        uint4 a = *(const uint4*)(p);
        uint4 bq = *(const uint4*)(p + 8);
        const u32* ap = (const u32*)&a;
        const u32* bp = (const u32*)&bq;
#pragma unroll
        for (int j = 0; j < 4; ++j) {
            acc[2 * j]     += __uint_as_float(ap[j] << 16);
            acc[2 * j + 1] += __uint_as_float(ap[j] & 0xFFFF0000u);
            acc[8 + 2 * j]     += __uint_as_float(bp[j] << 16);
            acc[8 + 2 * j + 1] += __uint_as_float(bp[j] & 0xFFFF0000u);
        }
    }
    u32 pk[8];
#pragma unroll
    for (int j = 0; j < 8; ++j)
        pk[j] = pkbf(acc[2 * j] * inv, acc[2 * j + 1] * inv);

    int bh = gr >> 12, q = gr & 4095;
    int b = bh >> 2, hh = bh & 3;
    u16* dst = attnT + ((size_t)(b * 4096 + q)) * 256 + hh * 64 + d0;
    *(uint4*)(dst) = make_uint4(pk[0], pk[1], pk[2], pk[3]);
    *(uint4*)(dst + 8) = make_uint4(pk[4], pk[5], pk[6], pk[7]);
}

// ---------------------------------------------------------------------------
// Kernel 5: output GEMM + bias + residual (R24 state, frozen).
// ---------------------------------------------------------------------------
__global__ __launch_bounds__(256) void out_gemm(
    const u16* __restrict__ attnT, const u16* __restrict__ W3,
    const float* __restrict__ bo, const float* __restrict__ x,
    float* __restrict__ out) {
    int b = blockIdx.y;
    int bx = blockIdx.x;
    int m0 = ((bx >> 3) & 3) * 64;
    int n0 = ((bx & 7) | ((bx >> 5) << 3)) * 64;

    __shared__ u16 a_s[2][64 * 40];
    __shared__ u16 b_s[2][64 * 40];

    int t = threadIdx.x;
    int lane = t & 63, wave = t >> 6;
    int wm = wave & 1, wn = wave >> 1;
    int r = lane & 15, qd = lane >> 4;

    const u16* Bsrc = attnT + (size_t)b * 4096 * 256;

    f32x4 acc[2][2];
#pragma unroll
    for (int i = 0; i < 2; ++i)
#pragma unroll
        for (int j = 0; j < 2; ++j) acc[i][j] = (f32x4){0.f, 0.f, 0.f, 0.f};

    int u = t & 127;
    int srow = u >> 1;
    int scp = (u & 1) * 16;

    uint4 p0, p1;
    auto load_regs = [&](int kk) {
        const u16* src = (t < 128)
            ? W3 + (m0 + srow) * 256 + kk + scp
            : Bsrc + (size_t)(n0 + srow) * 256 + kk + scp;
        p0 = *(const uint4*)(src);
        p1 = *(const uint4*)(src + 8);
    };
    auto write_buf = [&](int bsel) {
        u16* dst = (t < 128) ? (a_s[bsel] + srow * 40 + scp)
                             : (b_s[bsel] + srow * 40 + scp);
        *(uint4*)(dst) = p0;
        *(uint4*)(dst + 8) = p1;
    };

    load_regs(0);
    write_buf(0);
    BAR_LGKM();

    for (int it = 0; it < 8; ++it) {
        int cur = it & 1;
        bool more = (it + 1) < 8;
        if (more) load_regs((it + 1) * 32);

        bf16x8 af[2], bf[2];
#pragma unroll
        for (int mt = 0; mt < 2; ++mt)
            af[mt] = *(const bf16x8*)(a_s[cur] + (wm * 32 + mt * 16 + r) * 40 + qd * 8);
#pragma unroll
        for (int nt = 0; nt < 2; ++nt)
            bf[nt] = *(const bf16x8*)(b_s[cur] + (wn * 32 + nt * 16 + r) * 40 + qd * 8);
#pragma unroll
        for (int mt = 0; mt < 2; ++mt)
#pragma unroll
            for (int nt = 0; nt < 2; ++nt)
                acc[mt][nt] = MFMA(af[mt], bf[nt], acc[mt][nt]);

        if (more) write_buf(cur ^ 1);
        BAR_LGKM();
    }

#pragma unroll
    for (int mt = 0; mt < 2; ++mt) {
#pragma unroll
        for (int nt = 0; nt < 2; ++nt) {
#pragma unroll
            for (int j = 0; j < 4; ++j) {
                int o = m0 + wm * 32 + mt * 16 + qd * 4 + j;
                int s = n0 + wn * 32 + nt * 16 + r;
                size_t idx = (size_t)(b * 256 + o) * 4096 + s;
                out[idx] = acc[mt][nt][j] + bo[o] + x[idx];
            }
        }
    }
}

// ---------------------------------------------------------------------------
extern "C" void kernel_launch(void* const* d_in, const int* in_sizes, int n_in,
                              void* d_out, int out_size, void* d_ws, size_t ws_size,
                              hipStream_t stream) {
    const float* x = (const float*)d_in[0];
    const float* gn_w = (const float*)d_in[1];
    const float* gn_b = (const float*)d_in[2];
    const float* wq = (const float*)d_in[3];
    const float* wk = (const float*)d_in[4];
    const float* wv = (const float*)d_in[5];
    const float* wo = (const float*)d_in[6];
    const float* bo = (const float*)d_in[7];
    float* out = (float*)d_out;

    char* ws = (char*)d_ws;
    u16* attnT = (u16*)(ws);                        // [0,4M)
    u16* Q     = (u16*)(ws + (4u << 20));           // [b][h][s][d] (scaled log2e/16)
    u16* Kp    = (u16*)(ws + (8u << 20));           // [b][h][s][d]
    u16* Vp    = (u16*)(ws + (12u << 20));          // [b][h][d][s]
    u16* Wbf   = (u16*)(ws + (16u << 20));          // 512 KB
    float2* part = (float2*)(ws + (16u << 20) + 524288);

    size_t opart_off = (size_t)17 << 20;
    size_t osplit = 8ull * 4096 * 64 * 2;            // 4 MB per split
    int nsplit = (ws_size >= opart_off + 4 * osplit + 4ull * 32768 * 4 + 4096) ? 4 : 2;
    u16* Opart = (u16*)(ws + opart_off);
    float* Lpart = (float*)(ws + opart_off + (size_t)nsplit * osplit);

    prep_kernel<<<512, 256, 0, stream>>>(wq, wk, wv, wo, x, Wbf, part);
    qkv_gemm<<<dim3(128, 6), 256, 0, stream>>>(x, gn_w, gn_b, part, Wbf, Q, Kp, Vp);
    attn_kernel<1><<<dim3(8 * nsplit, 32), 256, 0, stream>>>(
        Q, Kp, Vp, Opart, Lpart, 128 / nsplit);
    attn_combine<<<512, 256, 0, stream>>>(Opart, Lpart, attnT, nsplit);
    out_gemm<<<dim3(256, 2), 256, 0, stream>>>(attnT, Wbf + 3 * 65536, bo, x, out);
}